// Round 5
// baseline (218.243 us; speedup 1.0000x reference)
//
#include <hip/hip_runtime.h>

// Unfold (im2col): x[8,64,224,224] f32, 3x3 kernel, pad=1, stride=1, dil=1
// out[b, c*9 + k, oh*224 + ow] = x[b, c, oh+ki-1, ow+kj-1] (0 outside), k = ki*3+kj
//
// Paired-quad mapping: lane l of wave w owns image-quads w*128+l and w*128+64+l.
// => every wave-level load/store instruction is a fully-packed contiguous 1KB
//    burst (R3's 8-consecutive-cols-per-thread made every instr half-density,
//    stride-32B). Each segment: 3 rows x (1 aligned float4 + 2 edge scalars),
//    3 kj shifts composed in-register, 9 float4 stores.

typedef float v4f __attribute__((ext_vector_type(4)));

constexpr int B = 8, C = 64, H = 224, W = 224;
constexpr int L  = H * W;          // 50176
constexpr int L4 = L / 4;          // 12544 quads per image; 12544 % 128 == 0
constexpr int W4 = W / 4;          // 56 quads per row
constexpr int CC = B * C;          // 512
constexpr unsigned QTOT   = (unsigned)CC * (unsigned)L4;  // 6,422,528 quads
constexpr unsigned TOTALT = QTOT / 2u;                    // 3,211,264 threads
// TOTALT / 256 = 12,544 blocks exactly.

__global__ __launch_bounds__(256) void unfold_pq_kernel(const float* __restrict__ x,
                                                        float* __restrict__ out) {
    unsigned t    = blockIdx.x * 256u + threadIdx.x;
    unsigned wv   = t >> 6;
    unsigned lane = t & 63u;
    unsigned qA   = wv * 128u + lane;          // wave covers quads [wv*128, wv*128+127]

    unsigned cc   = qA / (unsigned)L4;         // magic-mul; same cc for both segments
    unsigned remA = qA - cc * (unsigned)L4;

    const float* __restrict__ base = x + (size_t)cc * (size_t)L;

    v4f   q[2][3];
    float lf[2][3], rg[2][3];
    unsigned rem[2] = { remA, remA + 64u };    // remA + 64 < L4 guaranteed

    #pragma unroll
    for (int s = 0; s < 2; ++s) {
        unsigned r  = rem[s];
        int oh  = (int)(r / (unsigned)W4);     // magic-mul
        int col = (int)(r - (unsigned)oh * (unsigned)W4) * 4;   // 0..220, 16B-aligned
        #pragma unroll
        for (int ki = 0; ki < 3; ++ki) {
            int ih = oh + ki - 1;
            if (ih >= 0 && ih < H) {
                const float* __restrict__ src = base + ih * W;
                q[s][ki]  = *reinterpret_cast<const v4f*>(src + col);  // packed across lanes
                lf[s][ki] = (col > 0)     ? src[col - 1] : 0.f;
                rg[s][ki] = (col < W - 4) ? src[col + 4] : 0.f;
            } else {
                q[s][ki] = (v4f)0.f; lf[s][ki] = 0.f; rg[s][ki] = 0.f;
            }
        }
    }

    v4f* __restrict__ o = reinterpret_cast<v4f*>(out);
    size_t cb = (size_t)cc * 9u * (size_t)L4;
    #pragma unroll
    for (int s = 0; s < 2; ++s) {
        size_t ob = cb + (size_t)rem[s];
        #pragma unroll
        for (int ki = 0; ki < 3; ++ki) {
            v4f qq = q[s][ki];
            v4f a = { lf[s][ki], qq[0], qq[1], qq[2] };   // kj = 0
            v4f c = { qq[1], qq[2], qq[3], rg[s][ki] };   // kj = 2
            o[ob + (size_t)(ki * 3 + 0) * (size_t)L4] = a;
            o[ob + (size_t)(ki * 3 + 1) * (size_t)L4] = qq;
            o[ob + (size_t)(ki * 3 + 2) * (size_t)L4] = c;
        }
    }
}

extern "C" void kernel_launch(void* const* d_in, const int* in_sizes, int n_in,
                              void* d_out, int out_size, void* d_ws, size_t ws_size,
                              hipStream_t stream) {
    const float* x = (const float*)d_in[0];
    float* out = (float*)d_out;
    unsigned blocks = TOTALT / 256u;  // 12,544
    unfold_pq_kernel<<<dim3(blocks), dim3(256), 0, stream>>>(x, out);
}